// Round 6
// baseline (117.359 us; speedup 1.0000x reference)
//
#include <hip/hip_runtime.h>

// Householder reflection per row: out = z - 2 * v * (v.z) / (v.v)
// B = 1048576 rows, L = 64 fp32 per row.
//
// 16 lanes per row, 8 rows batched per thread (wave owns 32 consecutive rows).
// Each load instruction covers 4 rows = 1 KiB contiguous; 16 independent
// loads in flight per wave. NT hints: v streamed (bypass L3 retention),
// out streamed (no L3 allocation) -> z stays fully L3-resident (256 MiB = L3).
typedef float f32x4 __attribute__((ext_vector_type(4)));

__global__ void __launch_bounds__(256) HF_28063316312693_kernel(
        const float* __restrict__ v,
        const float* __restrict__ z,
        float* __restrict__ out) {
    const int tid    = blockIdx.x * blockDim.x + threadIdx.x;
    const int wave   = tid >> 6;       // owns rows [wave*32, wave*32+32)
    const int lane   = tid & 63;
    const int l4     = lane & 15;      // float4 slot within the row
    const int subrow = lane >> 4;      // 0..3

    const size_t b0 = ((size_t)wave * 32 + subrow) * 64 + (size_t)l4 * 4;

    const f32x4* vp = reinterpret_cast<const f32x4*>(v + b0);
    const f32x4* zp = reinterpret_cast<const f32x4*>(z + b0);

    f32x4 vv[8], zz[8];
    #pragma unroll
    for (int i = 0; i < 8; ++i) vv[i] = __builtin_nontemporal_load(vp + i * 64);
    #pragma unroll
    for (int i = 0; i < 8; ++i) zz[i] = zp[i * 64];

    float vz[8], nn[8];
    #pragma unroll
    for (int i = 0; i < 8; ++i) {
        vz[i] = vv[i].x * zz[i].x + vv[i].y * zz[i].y
              + vv[i].z * zz[i].z + vv[i].w * zz[i].w;
        nn[i] = vv[i].x * vv[i].x + vv[i].y * vv[i].y
              + vv[i].z * vv[i].z + vv[i].w * vv[i].w;
    }

    // 16 independent 4-step reductions across each aligned 16-lane group.
    #pragma unroll
    for (int off = 1; off < 16; off <<= 1) {
        #pragma unroll
        for (int i = 0; i < 8; ++i) {
            vz[i] += __shfl_xor(vz[i], off, 64);
            nn[i] += __shfl_xor(nn[i], off, 64);
        }
    }

    f32x4* op = reinterpret_cast<f32x4*>(out + b0);
    #pragma unroll
    for (int i = 0; i < 8; ++i) {
        const float s = -2.0f * vz[i] / nn[i];
        f32x4 o;
        o.x = fmaf(s, vv[i].x, zz[i].x);
        o.y = fmaf(s, vv[i].y, zz[i].y);
        o.z = fmaf(s, vv[i].z, zz[i].z);
        o.w = fmaf(s, vv[i].w, zz[i].w);
        __builtin_nontemporal_store(o, op + i * 64);
    }
}

extern "C" void kernel_launch(void* const* d_in, const int* in_sizes, int n_in,
                              void* d_out, int out_size, void* d_ws, size_t ws_size,
                              hipStream_t stream) {
    const float* v = (const float*)d_in[0];
    const float* z = (const float*)d_in[1];
    float* out = (float*)d_out;
    const int B = in_sizes[0] / 64;  // 1048576

    // 32 rows per wave, 4 waves per block -> 128 rows per block.
    const int block = 256;
    const int grid = B / 128;  // 8192, exact fit

    HF_28063316312693_kernel<<<grid, block, 0, stream>>>(v, z, out);
}